// Round 1
// baseline (1447.034 us; speedup 1.0000x reference)
//
#include <hip/hip_runtime.h>
#include <math.h>

// ---------------------------------------------------------------------------
// RNN_6451040879094: 2-layer tanh RNN step + output proj + log_softmax
//   h0 = tanh(x@W_ih0^T + b_ih0 + hid0@W_hh0^T + b_hh0)     [4096,1024]
//   h1 = tanh(h0@W_ih1^T + b_ih1 + hid1@W_hh1^T + b_hh1)    [4096,1024]
//   logits = [x|h0]@W_out^T + b_out                          [4096,4096]
//   out = log_softmax(logits, axis=1)
// d_out layout: out (4096*4096) ++ h0 (4096*1024) ++ h1 (4096*1024), fp32.
// Round 1: correctness-first fp32 tiled SGEMM, no workspace needed.
// ---------------------------------------------------------------------------

#define BM 64
#define BN 64
#define BK 32
#define PAD 4

// C[m][n] = act( sum_k Aa[m][k]*Wa[n][k] + sum_k Ab[m][k]*Wb[n][k] + ba[n] + bb[n] )
// K = 1024 per half. All pointers row-major with given leading dims (elements).
template <bool TANH>
__global__ __launch_bounds__(256) void gemm_dual(
    const float* __restrict__ Aa, int lda_a,
    const float* __restrict__ Ab, int lda_b,
    const float* __restrict__ Wa, int ldw_a,
    const float* __restrict__ Wb, int ldw_b,
    const float* __restrict__ ba, const float* __restrict__ bb,
    float* __restrict__ C, int ldc)
{
    __shared__ float As[BK][BM + PAD];   // As[k][m]
    __shared__ float Ws[BK][BN + PAD];   // Ws[k][n]

    const int tid = threadIdx.x;
    const int tx = tid & 15;         // output col group
    const int ty = tid >> 4;         // output row group
    const int row0 = blockIdx.y * BM;
    const int col0 = blockIdx.x * BN;

    // staging coords: each thread loads float4 at (sr, sc) and (sr+32, sc)
    const int sr = tid >> 3;         // 0..31
    const int sc = (tid & 7) * 4;    // 0,4,...,28

    float acc[4][4] = {{0.f}};

    for (int half = 0; half < 2; ++half) {
        const float* A = half ? Ab : Aa;
        const float* W = half ? Wb : Wa;
        const int lda = half ? lda_b : lda_a;
        const int ldw = half ? ldw_b : ldw_a;

        for (int k0 = 0; k0 < 1024; k0 += BK) {
            __syncthreads();
            float4 av0 = *(const float4*)(A + (size_t)(row0 + sr) * lda + k0 + sc);
            float4 av1 = *(const float4*)(A + (size_t)(row0 + sr + 32) * lda + k0 + sc);
            float4 wv0 = *(const float4*)(W + (size_t)(col0 + sr) * ldw + k0 + sc);
            float4 wv1 = *(const float4*)(W + (size_t)(col0 + sr + 32) * ldw + k0 + sc);
            As[sc + 0][sr] = av0.x;  As[sc + 1][sr] = av0.y;
            As[sc + 2][sr] = av0.z;  As[sc + 3][sr] = av0.w;
            As[sc + 0][sr + 32] = av1.x;  As[sc + 1][sr + 32] = av1.y;
            As[sc + 2][sr + 32] = av1.z;  As[sc + 3][sr + 32] = av1.w;
            Ws[sc + 0][sr] = wv0.x;  Ws[sc + 1][sr] = wv0.y;
            Ws[sc + 2][sr] = wv0.z;  Ws[sc + 3][sr] = wv0.w;
            Ws[sc + 0][sr + 32] = wv1.x;  Ws[sc + 1][sr + 32] = wv1.y;
            Ws[sc + 2][sr + 32] = wv1.z;  Ws[sc + 3][sr + 32] = wv1.w;
            __syncthreads();

#pragma unroll
            for (int kk = 0; kk < BK; ++kk) {
                float4 a = *(const float4*)&As[kk][ty * 4];
                float4 w = *(const float4*)&Ws[kk][tx * 4];
                acc[0][0] += a.x * w.x; acc[0][1] += a.x * w.y;
                acc[0][2] += a.x * w.z; acc[0][3] += a.x * w.w;
                acc[1][0] += a.y * w.x; acc[1][1] += a.y * w.y;
                acc[1][2] += a.y * w.z; acc[1][3] += a.y * w.w;
                acc[2][0] += a.z * w.x; acc[2][1] += a.z * w.y;
                acc[2][2] += a.z * w.z; acc[2][3] += a.z * w.w;
                acc[3][0] += a.w * w.x; acc[3][1] += a.w * w.y;
                acc[3][2] += a.w * w.z; acc[3][3] += a.w * w.w;
            }
        }
    }

    // epilogue: bias (+ optional second bias), optional tanh, float4 stores
    float bias[4];
#pragma unroll
    for (int j = 0; j < 4; ++j) {
        const int n = col0 + tx * 4 + j;
        float b = ba ? ba[n] : 0.f;
        if (bb) b += bb[n];
        bias[j] = b;
    }
#pragma unroll
    for (int i = 0; i < 4; ++i) {
        const int m = row0 + ty * 4 + i;
        float4 v;
        v.x = acc[i][0] + bias[0];
        v.y = acc[i][1] + bias[1];
        v.z = acc[i][2] + bias[2];
        v.w = acc[i][3] + bias[3];
        if (TANH) {
            v.x = tanhf(v.x); v.y = tanhf(v.y);
            v.z = tanhf(v.z); v.w = tanhf(v.w);
        }
        *(float4*)(C + (size_t)m * ldc + col0 + tx * 4) = v;
    }
}

// In-place row-wise log_softmax, one block per row of N=4096.
__global__ __launch_bounds__(256) void logsoftmax_inplace(float* __restrict__ logits)
{
    const int N = 4096;
    float* p = logits + (size_t)blockIdx.x * N;
    const int tid = threadIdx.x;
    const int lane = tid & 63;
    const int wv = tid >> 6;

    float v[16];
#pragma unroll
    for (int i = 0; i < 16; ++i) v[i] = p[tid + i * 256];

    float m = v[0];
#pragma unroll
    for (int i = 1; i < 16; ++i) m = fmaxf(m, v[i]);
#pragma unroll
    for (int off = 32; off; off >>= 1) m = fmaxf(m, __shfl_xor(m, off));

    __shared__ float redm[4];
    __shared__ float reds[4];
    if (lane == 0) redm[wv] = m;
    __syncthreads();
    m = fmaxf(fmaxf(redm[0], redm[1]), fmaxf(redm[2], redm[3]));

    float s = 0.f;
#pragma unroll
    for (int i = 0; i < 16; ++i) s += expf(v[i] - m);
#pragma unroll
    for (int off = 32; off; off >>= 1) s += __shfl_xor(s, off);
    if (lane == 0) reds[wv] = s;
    __syncthreads();
    s = reds[0] + reds[1] + reds[2] + reds[3];

    const float lse = m + logf(s);
#pragma unroll
    for (int i = 0; i < 16; ++i) p[tid + i * 256] = v[i] - lse;
}

extern "C" void kernel_launch(void* const* d_in, const int* in_sizes, int n_in,
                              void* d_out, int out_size, void* d_ws, size_t ws_size,
                              hipStream_t stream)
{
    (void)in_sizes; (void)n_in; (void)out_size; (void)d_ws; (void)ws_size;

    const float* input  = (const float*)d_in[0];   // [1,4096,1024]
    const float* hidden = (const float*)d_in[1];   // [2,4096,1024]
    const float* W_ih0  = (const float*)d_in[2];   // [1024,1024]
    const float* W_hh0  = (const float*)d_in[3];
    const float* b_ih0  = (const float*)d_in[4];
    const float* b_hh0  = (const float*)d_in[5];
    const float* W_ih1  = (const float*)d_in[6];
    const float* W_hh1  = (const float*)d_in[7];
    const float* b_ih1  = (const float*)d_in[8];
    const float* b_hh1  = (const float*)d_in[9];
    const float* W_out  = (const float*)d_in[10];  // [4096,2048]
    const float* b_out  = (const float*)d_in[11];

    float* out = (float*)d_out;            // [4096,4096] logits -> log_softmax
    float* h0  = out + (size_t)4096 * 4096;    // [4096,1024]
    float* h1  = h0 + (size_t)4096 * 1024;     // [4096,1024]
    const float* hid0 = hidden;
    const float* hid1 = hidden + (size_t)4096 * 1024;

    dim3 blk(256);

    // GEMM1: h0 = tanh(x@W_ih0^T + hid0@W_hh0^T + b_ih0 + b_hh0)
    dim3 g1(1024 / BN, 4096 / BM);
    hipLaunchKernelGGL((gemm_dual<true>), g1, blk, 0, stream,
                       input, 1024, hid0, 1024,
                       W_ih0, 1024, W_hh0, 1024,
                       b_ih0, b_hh0, h0, 1024);

    // GEMM2: h1 = tanh(h0@W_ih1^T + hid1@W_hh1^T + b_ih1 + b_hh1)
    hipLaunchKernelGGL((gemm_dual<true>), g1, blk, 0, stream,
                       h0, 1024, hid1, 1024,
                       W_ih1, 1024, W_hh1, 1024,
                       b_ih1, b_hh1, h1, 1024);

    // GEMM3: logits = x@W_out[:, :1024]^T + h0@W_out[:, 1024:]^T + b_out
    dim3 g3(4096 / BN, 4096 / BM);
    hipLaunchKernelGGL((gemm_dual<false>), g3, blk, 0, stream,
                       input, 1024, h0, 1024,
                       W_out, 2048, W_out + 1024, 2048,
                       b_out, nullptr, out, 4096);

    // log_softmax in place over each row of out
    hipLaunchKernelGGL(logsoftmax_inplace, dim3(4096), blk, 0, stream, out);
}

// Round 2
// 252.400 us; speedup vs baseline: 5.7331x; 5.7331x over previous
//
#include <hip/hip_runtime.h>
#include <math.h>

// ---------------------------------------------------------------------------
// RNN_6451040879094  (B=4096, I=H=1024, O=4096, fp32 in/out)
//   h0 = tanh([x|hid0] @ [W_ih0|W_hh0]^T + b_ih0 + b_hh0)
//   h1 = tanh([h0|hid1] @ [W_ih1|W_hh1]^T + b_ih1 + b_hh1)
//   logits = [x|h0] @ W_out^T + b_out ; out = log_softmax(logits)
// R2: bf16 MFMA GEMMs (m97 structure: 128x128 tile, BK=32, global_load_lds,
//     ds_read_b128 frags, 16x16x32 bf16 MFMA, fp32 accum), one-time fp32->bf16
//     conversion into d_ws (~56 MB).
// d_out: out(4096*4096) ++ h0(4096*1024) ++ h1(4096*1024), fp32.
// ---------------------------------------------------------------------------

typedef __attribute__((ext_vector_type(8))) short bf16x8;
typedef __attribute__((ext_vector_type(4))) float f32x4;

__device__ __forceinline__ unsigned short f2b_rne(float f) {
    unsigned int x = __float_as_uint(f);
    x += 0x7FFF + ((x >> 16) & 1);          // round-to-nearest-even
    return (unsigned short)(x >> 16);
}

__device__ __forceinline__ void gload_lds16(const void* g, void* l) {
    __builtin_amdgcn_global_load_lds(
        (const __attribute__((address_space(1))) void*)g,
        (__attribute__((address_space(3))) void*)l,
        16, 0, 0);
}

// fp32 -> bf16(bits) conversion, 8 elems/thread
__global__ __launch_bounds__(256) void f2b8(const float* __restrict__ src,
                                            unsigned short* __restrict__ dst,
                                            int n8)
{
    int i = blockIdx.x * 256 + threadIdx.x;
    if (i >= n8) return;
    const float4* s = (const float4*)src;
    float4 a = s[2 * (size_t)i];
    float4 b = s[2 * (size_t)i + 1];
    unsigned short t[8];
    t[0] = f2b_rne(a.x); t[1] = f2b_rne(a.y); t[2] = f2b_rne(a.z); t[3] = f2b_rne(a.w);
    t[4] = f2b_rne(b.x); t[5] = f2b_rne(b.y); t[6] = f2b_rne(b.z); t[7] = f2b_rne(b.w);
    *(uint4*)(dst + 8 * (size_t)i) = *(const uint4*)t;
}

// C[m][n] = act( sum_{k<1024} Aa[m][k]*Wa[n][k] + sum_{k<1024} Ab[m][k]*Wb[n][k]
//               + ba[n] (+ bb[n]) )
// A* : [M][lda] bf16 rows; W* : [N][ldw] bf16 rows. 128x128 tile, 4 waves.
template <bool TANH, bool WRITE_BF16>
__global__ __launch_bounds__(256) void gemm_mfma(
    const unsigned short* __restrict__ Aa,
    const unsigned short* __restrict__ Ab, int lda,
    const unsigned short* __restrict__ Wa,
    const unsigned short* __restrict__ Wb, int ldw,
    const float* __restrict__ ba, const float* __restrict__ bb,
    float* __restrict__ C, int ldc,
    unsigned short* __restrict__ Cb, int ldcb)
{
    __shared__ __align__(16) unsigned short As[128 * 32];
    __shared__ __align__(16) unsigned short Ws[128 * 32];

    const int tid = threadIdx.x;
    const int wid = tid >> 6;
    const int lane = tid & 63;
    const int wr = wid >> 1, wc = wid & 1;       // wave -> 64x64 quadrant
    const int row0 = blockIdx.y * 128;
    const int col0 = blockIdx.x * 128;

    // staging: 16B chunks, 4 per 32-elem row; wave w stages rows [w*16, w*16+16)
    // (i=0) and [64+w*16, ...) (i=1); LDS dest linear = chunk*16B
    const int c0 = wid * 64 + lane;
    const int c1 = 256 + wid * 64 + lane;
    const int r0 = c0 >> 2, o0 = (c0 & 3) * 8;
    const int r1 = c1 >> 2, o1 = (c1 & 3) * 8;
    unsigned short* ldsA0 = As + wid * 512;
    unsigned short* ldsA1 = As + 2048 + wid * 512;
    unsigned short* ldsW0 = Ws + wid * 512;
    unsigned short* ldsW1 = Ws + 2048 + wid * 512;

    const int fr = lane & 15;    // fragment row (A) / col (B)
    const int fk = lane >> 4;    // k-group (8 elems each)

    f32x4 acc[4][4] = {};

    for (int k0 = 0; k0 < 2048; k0 += 32) {
        const unsigned short* A = (k0 < 1024) ? (Aa + k0) : (Ab + (k0 - 1024));
        const unsigned short* W = (k0 < 1024) ? (Wa + k0) : (Wb + (k0 - 1024));
        gload_lds16(A + (size_t)(row0 + r0) * lda + o0, ldsA0);
        gload_lds16(A + (size_t)(row0 + r1) * lda + o1, ldsA1);
        gload_lds16(W + (size_t)(col0 + r0) * ldw + o0, ldsW0);
        gload_lds16(W + (size_t)(col0 + r1) * ldw + o1, ldsW1);
        __syncthreads();

        bf16x8 af[4], wf[4];
#pragma unroll
        for (int m = 0; m < 4; ++m)
            af[m] = *(const bf16x8*)&As[(wr * 64 + m * 16 + fr) * 32 + fk * 8];
#pragma unroll
        for (int n = 0; n < 4; ++n)
            wf[n] = *(const bf16x8*)&Ws[(wc * 64 + n * 16 + fr) * 32 + fk * 8];
#pragma unroll
        for (int m = 0; m < 4; ++m)
#pragma unroll
            for (int n = 0; n < 4; ++n)
                acc[m][n] = __builtin_amdgcn_mfma_f32_16x16x32_bf16(
                    af[m], wf[n], acc[m][n], 0, 0, 0);
        __syncthreads();
    }

    // epilogue: C/D layout col = lane&15, row = (lane>>4)*4 + j  [m89/m91]
    float biasv[4];
#pragma unroll
    for (int n = 0; n < 4; ++n) {
        int col = col0 + wc * 64 + n * 16 + fr;
        float b = ba ? ba[col] : 0.f;
        if (bb) b += bb[col];
        biasv[n] = b;
    }
#pragma unroll
    for (int m = 0; m < 4; ++m) {
#pragma unroll
        for (int n = 0; n < 4; ++n) {
            const int col = col0 + wc * 64 + n * 16 + fr;
#pragma unroll
            for (int j = 0; j < 4; ++j) {
                const int r = row0 + wr * 64 + m * 16 + fk * 4 + j;
                float v = acc[m][n][j] + biasv[n];
                if (TANH) v = tanhf(v);
                C[(size_t)r * ldc + col] = v;
                if (WRITE_BF16) Cb[(size_t)r * ldcb + col] = f2b_rne(v);
            }
        }
    }
}

// In-place row-wise log_softmax, one block per row of N=4096.
__global__ __launch_bounds__(256) void logsoftmax_inplace(float* __restrict__ logits)
{
    const int N = 4096;
    float* p = logits + (size_t)blockIdx.x * N;
    const int tid = threadIdx.x;
    const int lane = tid & 63;
    const int wv = tid >> 6;

    float v[16];
#pragma unroll
    for (int i = 0; i < 16; ++i) v[i] = p[tid + i * 256];

    float m = v[0];
#pragma unroll
    for (int i = 1; i < 16; ++i) m = fmaxf(m, v[i]);
#pragma unroll
    for (int off = 32; off; off >>= 1) m = fmaxf(m, __shfl_xor(m, off));

    __shared__ float redm[4];
    __shared__ float reds[4];
    if (lane == 0) redm[wv] = m;
    __syncthreads();
    m = fmaxf(fmaxf(redm[0], redm[1]), fmaxf(redm[2], redm[3]));

    float s = 0.f;
#pragma unroll
    for (int i = 0; i < 16; ++i) s += expf(v[i] - m);
#pragma unroll
    for (int off = 32; off; off >>= 1) s += __shfl_xor(s, off);
    if (lane == 0) reds[wv] = s;
    __syncthreads();
    s = reds[0] + reds[1] + reds[2] + reds[3];

    const float lse = m + logf(s);
#pragma unroll
    for (int i = 0; i < 16; ++i) p[tid + i * 256] = v[i] - lse;
}

extern "C" void kernel_launch(void* const* d_in, const int* in_sizes, int n_in,
                              void* d_out, int out_size, void* d_ws, size_t ws_size,
                              hipStream_t stream)
{
    (void)in_sizes; (void)n_in; (void)out_size; (void)ws_size;

    const float* input  = (const float*)d_in[0];   // [1,4096,1024]
    const float* hidden = (const float*)d_in[1];   // [2,4096,1024]
    const float* W_ih0  = (const float*)d_in[2];   // [1024,1024]
    const float* W_hh0  = (const float*)d_in[3];
    const float* b_ih0  = (const float*)d_in[4];
    const float* b_hh0  = (const float*)d_in[5];
    const float* W_ih1  = (const float*)d_in[6];
    const float* W_hh1  = (const float*)d_in[7];
    const float* b_ih1  = (const float*)d_in[8];
    const float* b_hh1  = (const float*)d_in[9];
    const float* W_out  = (const float*)d_in[10];  // [4096,2048]
    const float* b_out  = (const float*)d_in[11];

    float* out = (float*)d_out;                    // [4096,4096]
    float* h0  = out + (size_t)4096 * 4096;        // [4096,1024]
    float* h1  = h0 + (size_t)4096 * 1024;

    // workspace bf16 buffers (56 MB total)
    unsigned short* xb    = (unsigned short*)d_ws;                 // 4M
    unsigned short* hidb  = xb    + (size_t)4096 * 1024;           // 8M (both layers)
    unsigned short* h0b   = hidb  + (size_t)2 * 4096 * 1024;       // 4M
    unsigned short* Wih0b = h0b   + (size_t)4096 * 1024;           // 1M
    unsigned short* Whh0b = Wih0b + (size_t)1024 * 1024;
    unsigned short* Wih1b = Whh0b + (size_t)1024 * 1024;
    unsigned short* Whh1b = Wih1b + (size_t)1024 * 1024;
    unsigned short* Woutb = Whh1b + (size_t)1024 * 1024;           // 8M
    unsigned short* hid0b = hidb;
    unsigned short* hid1b = hidb + (size_t)4096 * 1024;

    dim3 blk(256);
    auto cvt = [&](const float* s, unsigned short* d, size_t n) {
        int n8 = (int)(n / 8);
        hipLaunchKernelGGL(f2b8, dim3((n8 + 255) / 256), blk, 0, stream, s, d, n8);
    };

    cvt(input, xb,    (size_t)4096 * 1024);
    cvt(hidden, hidb, (size_t)2 * 4096 * 1024);
    cvt(W_ih0, Wih0b, (size_t)1024 * 1024);
    cvt(W_hh0, Whh0b, (size_t)1024 * 1024);
    cvt(W_ih1, Wih1b, (size_t)1024 * 1024);
    cvt(W_hh1, Whh1b, (size_t)1024 * 1024);
    cvt(W_out, Woutb, (size_t)4096 * 2048);

    // GEMM1: h0 = tanh(x@Wih0^T + hid0@Whh0^T + b_ih0 + b_hh0); also h0b (bf16)
    dim3 g1(1024 / 128, 4096 / 128);
    hipLaunchKernelGGL((gemm_mfma<true, true>), g1, blk, 0, stream,
                       xb, hid0b, 1024, Wih0b, Whh0b, 1024,
                       b_ih0, b_hh0, h0, 1024, h0b, 1024);

    // GEMM2: h1 = tanh(h0@Wih1^T + hid1@Whh1^T + b_ih1 + b_hh1)
    hipLaunchKernelGGL((gemm_mfma<true, false>), g1, blk, 0, stream,
                       h0b, hid1b, 1024, Wih1b, Whh1b, 1024,
                       b_ih1, b_hh1, h1, 1024, (unsigned short*)nullptr, 0);

    // GEMM3: logits = x@W_out[:, :1024]^T + h0@W_out[:, 1024:]^T + b_out
    dim3 g3(4096 / 128, 4096 / 128);
    hipLaunchKernelGGL((gemm_mfma<false, false>), g3, blk, 0, stream,
                       xb, h0b, 1024, Woutb, Woutb + 1024, 2048,
                       b_out, (const float*)nullptr, out, 4096,
                       (unsigned short*)nullptr, 0);

    hipLaunchKernelGGL(logsoftmax_inplace, dim3(4096), blk, 0, stream, out);
}

// Round 3
// 222.757 us; speedup vs baseline: 6.4960x; 1.1331x over previous
//
#include <hip/hip_runtime.h>
#include <math.h>

// ---------------------------------------------------------------------------
// RNN_6451040879094  (B=4096, I=H=1024, O=4096, fp32 in/out)
// R3: - one fused fp32->bf16 conversion kernel (7 segments)
//     - GEMM1 at 128x64 tiles (512 blocks = 2/CU)
//     - GEMM2+GEMM3 merged into ONE dispatch (independent given h0)
//     - LDS chunk swizzle (source-permute + read-permute, rule #21) to kill
//       ds_read_b128 bank conflicts; linear LDS dest for global_load_lds
//     - XCD-aware bijective block swizzle per role
// d_out: out(4096*4096) ++ h0(4096*1024) ++ h1(4096*1024), fp32.
// ---------------------------------------------------------------------------

typedef __attribute__((ext_vector_type(8))) short bf16x8;
typedef __attribute__((ext_vector_type(4))) float f32x4;

__device__ __forceinline__ unsigned short f2b_rne(float f) {
    unsigned int x = __float_as_uint(f);
    x += 0x7FFF + ((x >> 16) & 1);          // round-to-nearest-even
    return (unsigned short)(x >> 16);
}

__device__ __forceinline__ void gload_lds16(const void* g, void* l) {
    __builtin_amdgcn_global_load_lds(
        (const __attribute__((address_space(1))) void*)g,
        (__attribute__((address_space(3))) void*)l,
        16, 0, 0);
}

// ---------------- fused fp32 -> bf16 conversion (7 segments) ----------------
struct CvtSeg { const float* src; unsigned short* dst; unsigned n8; };
struct CvtArgs { CvtSeg seg[7]; };

__global__ __launch_bounds__(256) void f2b_multi(CvtArgs a)
{
    unsigned i = blockIdx.x * 256 + threadIdx.x;
#pragma unroll
    for (int s = 0; s < 7; ++s) {
        if (i < a.seg[s].n8) {
            const float4* src = (const float4*)a.seg[s].src;
            float4 u = src[2 * (size_t)i];
            float4 v = src[2 * (size_t)i + 1];
            unsigned short t[8] = {
                f2b_rne(u.x), f2b_rne(u.y), f2b_rne(u.z), f2b_rne(u.w),
                f2b_rne(v.x), f2b_rne(v.y), f2b_rne(v.z), f2b_rne(v.w)};
            *(uint4*)(a.seg[s].dst + 8 * (size_t)i) = *(const uint4*)t;
            return;
        }
        i -= a.seg[s].n8;
    }
}

// ---------------- bf16 MFMA GEMM, dual-K (two 1024 halves) ------------------
// C[m][n] = act( sum_k Aa[m][k]Wa[n][k] + sum_k Ab[m][k]Wb[n][k] + ba[n](+bb[n]) )
struct GemmP {
    const unsigned short *Aa, *Ab; int lda;
    const unsigned short *Wa, *Wb; int ldw;
    const float *ba, *bb;
    float* C; int ldc;
    unsigned short* Cb; int ldcb;   // optional bf16 copy of C
    int nx;                         // tiles along N
    int nb;                         // blocks in this role (multiple of 8)
    int do_tanh;
};

template<int BM, int BN>
__global__ __launch_bounds__(256) void gemm_bf16(GemmP pA, GemmP pB, int nA)
{
    constexpr int FM = BM / 32;     // 16-row frags per wave (2x2 wave grid)
    constexpr int FN = BN / 32;
    __shared__ __align__(16) unsigned short As[BM * 32];
    __shared__ __align__(16) unsigned short Ws[BN * 32];

    GemmP p;
    int bid = blockIdx.x;
    if (bid < nA) { p = pA; } else { p = pB; bid -= nA; }
    // XCD-aware bijective swizzle (nb % 8 == 0)
    bid = (bid & 7) * (p.nb >> 3) + (bid >> 3);
    const int row0 = (bid / p.nx) * BM;
    const int col0 = (bid % p.nx) * BN;

    const int tid = threadIdx.x;
    const int wid = tid >> 6, lane = tid & 63;
    const int wr = wid >> 1, wc = wid & 1;
    const int fr = lane & 15, fk = lane >> 4;

    f32x4 acc[FM][FN] = {};

    for (int h = 0; h < 2; ++h) {
        const unsigned short* A = h ? p.Ab : p.Aa;
        const unsigned short* W = h ? p.Wb : p.Wa;
        for (int k0 = 0; k0 < 1024; k0 += 32) {
            // stage: LDS dest linear; global source chunk-swizzled o^((r>>1)&3)
#pragma unroll
            for (int i = 0; i < BM / 64; ++i) {
                int c = i * 256 + wid * 64 + lane;
                int r = c >> 2, ol = c & 3;
                int os = ol ^ ((r >> 1) & 3);
                gload_lds16(A + (size_t)(row0 + r) * p.lda + k0 + os * 8,
                            As + (i * 256 + wid * 64) * 8);
            }
#pragma unroll
            for (int i = 0; i < BN / 64; ++i) {
                int c = i * 256 + wid * 64 + lane;
                int r = c >> 2, ol = c & 3;
                int os = ol ^ ((r >> 1) & 3);
                gload_lds16(W + (size_t)(col0 + r) * p.ldw + k0 + os * 8,
                            Ws + (i * 256 + wid * 64) * 8);
            }
            __syncthreads();

            bf16x8 af[FM], wf[FN];
#pragma unroll
            for (int m = 0; m < FM; ++m) {
                int r = wr * (BM / 2) + m * 16 + fr;
                af[m] = *(const bf16x8*)&As[r * 32 + ((fk ^ ((r >> 1) & 3)) * 8)];
            }
#pragma unroll
            for (int n = 0; n < FN; ++n) {
                int r = wc * (BN / 2) + n * 16 + fr;
                wf[n] = *(const bf16x8*)&Ws[r * 32 + ((fk ^ ((r >> 1) & 3)) * 8)];
            }
#pragma unroll
            for (int m = 0; m < FM; ++m)
#pragma unroll
                for (int n = 0; n < FN; ++n)
                    acc[m][n] = __builtin_amdgcn_mfma_f32_16x16x32_bf16(
                        af[m], wf[n], acc[m][n], 0, 0, 0);
            __syncthreads();
        }
    }

    // epilogue: C/D layout col = lane&15, row = (lane>>4)*4 + j
    const bool dot = p.do_tanh != 0;
    float biasv[FN];
#pragma unroll
    for (int n = 0; n < FN; ++n) {
        int col = col0 + wc * (BN / 2) + n * 16 + fr;
        float b = p.ba[col];
        if (p.bb) b += p.bb[col];
        biasv[n] = b;
    }
#pragma unroll
    for (int m = 0; m < FM; ++m) {
#pragma unroll
        for (int n = 0; n < FN; ++n) {
            const int col = col0 + wc * (BN / 2) + n * 16 + fr;
#pragma unroll
            for (int j = 0; j < 4; ++j) {
                const int r = row0 + wr * (BM / 2) + m * 16 + fk * 4 + j;
                float v = acc[m][n][j] + biasv[n];
                if (dot) v = tanhf(v);
                p.C[(size_t)r * p.ldc + col] = v;
                if (p.Cb) p.Cb[(size_t)r * p.ldcb + col] = f2b_rne(v);
            }
        }
    }
}

// ---------------- in-place row log_softmax, N=4096 --------------------------
__global__ __launch_bounds__(256) void logsoftmax_inplace(float* __restrict__ logits)
{
    const int N = 4096;
    float* p = logits + (size_t)blockIdx.x * N;
    const int tid = threadIdx.x;
    const int lane = tid & 63;
    const int wv = tid >> 6;

    float v[16];
#pragma unroll
    for (int i = 0; i < 16; ++i) v[i] = p[tid + i * 256];

    float m = v[0];
#pragma unroll
    for (int i = 1; i < 16; ++i) m = fmaxf(m, v[i]);
#pragma unroll
    for (int off = 32; off; off >>= 1) m = fmaxf(m, __shfl_xor(m, off));

    __shared__ float redm[4];
    __shared__ float reds[4];
    if (lane == 0) redm[wv] = m;
    __syncthreads();
    m = fmaxf(fmaxf(redm[0], redm[1]), fmaxf(redm[2], redm[3]));

    float s = 0.f;
#pragma unroll
    for (int i = 0; i < 16; ++i) s += expf(v[i] - m);
#pragma unroll
    for (int off = 32; off; off >>= 1) s += __shfl_xor(s, off);
    if (lane == 0) reds[wv] = s;
    __syncthreads();
    s = reds[0] + reds[1] + reds[2] + reds[3];

    const float lse = m + logf(s);
#pragma unroll
    for (int i = 0; i < 16; ++i) p[tid + i * 256] = v[i] - lse;
}

extern "C" void kernel_launch(void* const* d_in, const int* in_sizes, int n_in,
                              void* d_out, int out_size, void* d_ws, size_t ws_size,
                              hipStream_t stream)
{
    (void)in_sizes; (void)n_in; (void)out_size; (void)ws_size;

    const float* input  = (const float*)d_in[0];
    const float* hidden = (const float*)d_in[1];
    const float* b_ih0  = (const float*)d_in[4];
    const float* b_hh0  = (const float*)d_in[5];
    const float* b_ih1  = (const float*)d_in[8];
    const float* b_hh1  = (const float*)d_in[9];
    const float* b_out  = (const float*)d_in[11];

    float* out = (float*)d_out;                    // [4096,4096]
    float* h0  = out + (size_t)4096 * 4096;        // [4096,1024]
    float* h1  = h0 + (size_t)4096 * 1024;

    // bf16 workspace
    unsigned short* xb    = (unsigned short*)d_ws;
    unsigned short* hidb  = xb    + (size_t)4096 * 1024;
    unsigned short* h0b   = hidb  + (size_t)2 * 4096 * 1024;
    unsigned short* Wih0b = h0b   + (size_t)4096 * 1024;
    unsigned short* Whh0b = Wih0b + (size_t)1024 * 1024;
    unsigned short* Wih1b = Whh0b + (size_t)1024 * 1024;
    unsigned short* Whh1b = Wih1b + (size_t)1024 * 1024;
    unsigned short* Woutb = Whh1b + (size_t)1024 * 1024;
    unsigned short* hid0b = hidb;
    unsigned short* hid1b = hidb + (size_t)4096 * 1024;

    // fused conversions (n8 totals: 512K + 1M + 4*128K + 1M = 3072K)
    CvtArgs ca;
    ca.seg[0] = { input,                 xb,    4096u * 1024 / 8 };
    ca.seg[1] = { hidden,                hidb,  2u * 4096 * 1024 / 8 };
    ca.seg[2] = { (const float*)d_in[2], Wih0b, 1024u * 1024 / 8 };
    ca.seg[3] = { (const float*)d_in[3], Whh0b, 1024u * 1024 / 8 };
    ca.seg[4] = { (const float*)d_in[6], Wih1b, 1024u * 1024 / 8 };
    ca.seg[5] = { (const float*)d_in[7], Whh1b, 1024u * 1024 / 8 };
    ca.seg[6] = { (const float*)d_in[10],Woutb, 4096u * 2048 / 8 };
    hipLaunchKernelGGL(f2b_multi, dim3(12288), dim3(256), 0, stream, ca);

    // GEMM1: h0 = tanh(x@Wih0^T + hid0@Whh0^T + b), 128x64 tiles, 512 blocks
    GemmP p1;
    p1.Aa = xb;    p1.Ab = hid0b; p1.lda = 1024;
    p1.Wa = Wih0b; p1.Wb = Whh0b; p1.ldw = 1024;
    p1.ba = b_ih0; p1.bb = b_hh0;
    p1.C = h0; p1.ldc = 1024; p1.Cb = h0b; p1.ldcb = 1024;
    p1.nx = 16; p1.nb = 512; p1.do_tanh = 1;
    hipLaunchKernelGGL((gemm_bf16<128, 64>), dim3(512), dim3(256), 0, stream,
                       p1, p1, 512);

    // merged: GEMM3 (1024 blocks) + GEMM2 (256 blocks), both 128x128
    GemmP p3;
    p3.Aa = xb;    p3.Ab = h0b;          p3.lda = 1024;
    p3.Wa = Woutb; p3.Wb = Woutb + 1024; p3.ldw = 2048;
    p3.ba = b_out; p3.bb = nullptr;
    p3.C = out; p3.ldc = 4096; p3.Cb = nullptr; p3.ldcb = 0;
    p3.nx = 32; p3.nb = 1024; p3.do_tanh = 0;

    GemmP p2;
    p2.Aa = h0b;   p2.Ab = hid1b; p2.lda = 1024;
    p2.Wa = Wih1b; p2.Wb = Whh1b; p2.ldw = 1024;
    p2.ba = b_ih1; p2.bb = b_hh1;
    p2.C = h1; p2.ldc = 1024; p2.Cb = nullptr; p2.ldcb = 0;
    p2.nx = 8; p2.nb = 256; p2.do_tanh = 1;

    hipLaunchKernelGGL((gemm_bf16<128, 128>), dim3(1280), dim3(256), 0, stream,
                       p3, p2, 1024);

    hipLaunchKernelGGL(logsoftmax_inplace, dim3(4096), dim3(256), 0, stream, out);
}

// Round 4
// 200.262 us; speedup vs baseline: 7.2257x; 1.1123x over previous
//
#include <hip/hip_runtime.h>
#include <math.h>

// ---------------------------------------------------------------------------
// RNN_6451040879094  (B=4096, I=H=1024, O=4096, fp32 in/out)
// R4: - GEMM3 -> 8-phase 256x256 schedule (T2 swizzle + T3/T4 counted vmcnt +
//       T5 setprio), 256 blocks x 512 thr, LDS 128KB, raw barriers
//     - GEMM2 (2-phase 128^2) fused with log_softmax in one dispatch
//     - GEMM1 2-phase 128x64 unchanged; fused fp32->bf16 cvt unchanged
// d_out: out(4096*4096) ++ h0(4096*1024) ++ h1(4096*1024), fp32.
// ---------------------------------------------------------------------------

typedef __attribute__((ext_vector_type(8))) short bf16x8;
typedef __attribute__((ext_vector_type(4))) float f32x4;

__device__ __forceinline__ unsigned short f2b_rne(float f) {
    unsigned int x = __float_as_uint(f);
    x += 0x7FFF + ((x >> 16) & 1);
    return (unsigned short)(x >> 16);
}

__device__ __forceinline__ void gload_lds16(const void* g, void* l) {
    __builtin_amdgcn_global_load_lds(
        (const __attribute__((address_space(1))) void*)g,
        (__attribute__((address_space(3))) void*)l,
        16, 0, 0);
}

// ---------------- fused fp32 -> bf16 conversion (7 segments) ----------------
struct CvtSeg { const float* src; unsigned short* dst; unsigned n8; };
struct CvtArgs { CvtSeg seg[7]; };

__global__ __launch_bounds__(256) void f2b_multi(CvtArgs a)
{
    unsigned i = blockIdx.x * 256 + threadIdx.x;
#pragma unroll
    for (int s = 0; s < 7; ++s) {
        if (i < a.seg[s].n8) {
            const float4* src = (const float4*)a.seg[s].src;
            float4 u = src[2 * (size_t)i];
            float4 v = src[2 * (size_t)i + 1];
            unsigned short t[8] = {
                f2b_rne(u.x), f2b_rne(u.y), f2b_rne(u.z), f2b_rne(u.w),
                f2b_rne(v.x), f2b_rne(v.y), f2b_rne(v.z), f2b_rne(v.w)};
            *(uint4*)(a.seg[s].dst + 8 * (size_t)i) = *(const uint4*)t;
            return;
        }
        i -= a.seg[s].n8;
    }
}

// ================= 2-phase 128xBN GEMM (GEMM1 / GEMM2 roles) ================
struct GemmP {
    const unsigned short *Aa, *Ab; int lda;
    const unsigned short *Wa, *Wb; int ldw;
    const float *ba, *bb;
    float* C; int ldc;
    unsigned short* Cb; int ldcb;
    int nx, nb, do_tanh;
};

template<int BM, int BN>
__device__ __forceinline__ void gemm2p_body(
    const GemmP& p, int bid0, unsigned short* As, unsigned short* Ws, int tid)
{
    constexpr int FM = BM / 32;
    constexpr int FN = BN / 32;
    int bid = (bid0 & 7) * (p.nb >> 3) + (bid0 >> 3);
    const int row0 = (bid / p.nx) * BM;
    const int col0 = (bid % p.nx) * BN;

    const int wid = tid >> 6, lane = tid & 63;
    const int wr = wid >> 1, wc = wid & 1;
    const int fr = lane & 15, fk = lane >> 4;

    f32x4 acc[FM][FN] = {};

    for (int h = 0; h < 2; ++h) {
        const unsigned short* A = h ? p.Ab : p.Aa;
        const unsigned short* W = h ? p.Wb : p.Wa;
        for (int k0 = 0; k0 < 1024; k0 += 32) {
#pragma unroll
            for (int i = 0; i < BM / 64; ++i) {
                int c = i * 256 + wid * 64 + lane;
                int r = c >> 2, ol = c & 3;
                int os = ol ^ ((r >> 1) & 3);
                gload_lds16(A + (size_t)(row0 + r) * p.lda + k0 + os * 8,
                            As + (i * 256 + wid * 64) * 8);
            }
#pragma unroll
            for (int i = 0; i < BN / 64; ++i) {
                int c = i * 256 + wid * 64 + lane;
                int r = c >> 2, ol = c & 3;
                int os = ol ^ ((r >> 1) & 3);
                gload_lds16(W + (size_t)(col0 + r) * p.ldw + k0 + os * 8,
                            Ws + (i * 256 + wid * 64) * 8);
            }
            __syncthreads();

            bf16x8 af[FM], wf[FN];
#pragma unroll
            for (int m = 0; m < FM; ++m) {
                int r = wr * (BM / 2) + m * 16 + fr;
                af[m] = *(const bf16x8*)&As[r * 32 + ((fk ^ ((r >> 1) & 3)) * 8)];
            }
#pragma unroll
            for (int n = 0; n < FN; ++n) {
                int r = wc * (BN / 2) + n * 16 + fr;
                wf[n] = *(const bf16x8*)&Ws[r * 32 + ((fk ^ ((r >> 1) & 3)) * 8)];
            }
#pragma unroll
            for (int m = 0; m < FM; ++m)
#pragma unroll
                for (int n = 0; n < FN; ++n)
                    acc[m][n] = __builtin_amdgcn_mfma_f32_16x16x32_bf16(
                        af[m], wf[n], acc[m][n], 0, 0, 0);
            __syncthreads();
        }
    }

    const bool dot = p.do_tanh != 0;
#pragma unroll
    for (int n = 0; n < FN; ++n) {
        const int col = col0 + wc * (BN / 2) + n * 16 + fr;
        float b = p.ba[col];
        if (p.bb) b += p.bb[col];
#pragma unroll
        for (int m = 0; m < FM; ++m) {
#pragma unroll
            for (int j = 0; j < 4; ++j) {
                const int r = row0 + wr * (BM / 2) + m * 16 + fk * 4 + j;
                float v = acc[m][n][j] + b;
                if (dot) v = tanhf(v);
                p.C[(size_t)r * p.ldc + col] = v;
                if (p.Cb) p.Cb[(size_t)r * p.ldcb + col] = f2b_rne(v);
            }
        }
    }
}

__global__ __launch_bounds__(256) void gemm1_k(GemmP p)
{
    __shared__ __align__(16) unsigned short As[128 * 32];
    __shared__ __align__(16) unsigned short Ws[64 * 32];
    gemm2p_body<128, 64>(p, blockIdx.x, As, Ws, threadIdx.x);
}

// ---------------- row log_softmax as device function ------------------------
__device__ __forceinline__ void logsoftmax_row(float* __restrict__ p, int tid)
{
    const int lane = tid & 63;
    const int wv = tid >> 6;
    __shared__ float redm[4];
    __shared__ float reds[4];

    float v[16];
#pragma unroll
    for (int i = 0; i < 16; ++i) v[i] = p[tid + i * 256];

    float m = v[0];
#pragma unroll
    for (int i = 1; i < 16; ++i) m = fmaxf(m, v[i]);
#pragma unroll
    for (int off = 32; off; off >>= 1) m = fmaxf(m, __shfl_xor(m, off));
    if (lane == 0) redm[wv] = m;
    __syncthreads();
    m = fmaxf(fmaxf(redm[0], redm[1]), fmaxf(redm[2], redm[3]));

    float s = 0.f;
#pragma unroll
    for (int i = 0; i < 16; ++i) s += expf(v[i] - m);
#pragma unroll
    for (int off = 32; off; off >>= 1) s += __shfl_xor(s, off);
    if (lane == 0) reds[wv] = s;
    __syncthreads();
    s = reds[0] + reds[1] + reds[2] + reds[3];

    const float lse = m + logf(s);
#pragma unroll
    for (int i = 0; i < 16; ++i) p[tid + i * 256] = v[i] - lse;
}

// GEMM2 (blocks 0..255) + log_softmax rows (blocks 256..4351), one dispatch
__global__ __launch_bounds__(256) void g2sm_k(GemmP p, float* __restrict__ logits)
{
    if (blockIdx.x < 256) {
        __shared__ __align__(16) unsigned short As[128 * 32];
        __shared__ __align__(16) unsigned short Ws[128 * 32];
        gemm2p_body<128, 128>(p, blockIdx.x, As, Ws, threadIdx.x);
    } else {
        logsoftmax_row(logits + (size_t)(blockIdx.x - 256) * 4096, threadIdx.x);
    }
}

// ================= 8-phase 256x256 GEMM (GEMM3) =============================
// C = [Aa|Ab] @ [Wa|Wb]^T + bias.  K = 1024 + 1024, NT = 32 K-tiles of 64.
// LDS: A,B each [2 dbuf][2 half][128][64] bf16 (64KB + 64KB).
// A-half h holds tile rows {h*64..h*64+63} u {128+h*64..+63};
// B-half h holds tile cols in 32-stripes at offset h*32 mod 64.
// Chunk swizzle: LDS chunk cc of row i holds global k-chunk cc^(i&7).

__device__ __forceinline__ void stage_half8(
    const unsigned short* __restrict__ src, int ld, int base_rc, int tau, int h,
    unsigned short* lds, int wid, int lane, bool isA)
{
    unsigned short* dst = lds + (tau & 1) * 16384 + h * 8192 + wid * 1024;
    const int k0 = (tau & 15) << 6;
#pragma unroll
    for (int i = 0; i < 2; ++i) {
        int c = wid * 128 + i * 64 + lane;
        int ir = c >> 3, cc = c & 7;
        int grow = isA ? (base_rc + h * 64 + (ir & 63) + ((ir >> 6) << 7))
                       : (base_rc + h * 32 + (ir & 31) + ((ir >> 5) << 6));
        int gk = k0 + (((cc ^ ir) & 7) << 3);
        gload_lds16(src + (size_t)grow * ld + gk, dst + i * 512);
    }
}

__global__ __launch_bounds__(512, 2) void gemm8p(
    const unsigned short* __restrict__ Aa, const unsigned short* __restrict__ Ab,
    const unsigned short* __restrict__ Wa, const unsigned short* __restrict__ Wb,
    int lda, int ldw, const float* __restrict__ bias,
    float* __restrict__ C, int ldc, int nx)
{
    constexpr int NT = 32;
    __shared__ __align__(16) unsigned short As[2 * 2 * 128 * 64];   // 64 KB
    __shared__ __align__(16) unsigned short Bs[2 * 2 * 128 * 64];   // 64 KB

    int bid = blockIdx.x;
    bid = (bid & 7) * 32 + (bid >> 3);            // XCD swizzle (256 = 8*32)
    const int row0 = (bid / nx) * 256;
    const int col0 = (bid % nx) * 256;

    const int tid = threadIdx.x;
    const int wid = tid >> 6, lane = tid & 63;
    const int wr = wid >> 2, wc = wid & 3;        // 2 x 4 wave grid
    const int fr = lane & 15, fk = lane >> 4;
    const int ch0 = fk ^ (fr & 7);                // swizzled k-chunk, kk=0
    const int ch1 = ch0 ^ 4;                      // kk=1

#define STA8(tau, h) stage_half8(((tau) < 16 ? Aa : Ab), lda, row0, (tau), (h), As, wid, lane, true)
#define STB8(tau, h) stage_half8(((tau) < 16 ? Wa : Wb), ldw, col0, (tau), (h), Bs, wid, lane, false)

    f32x4 acc[2][2][4][2] = {};

    // prologue: tile0 (4 halves) + tile1 Bh0, Ah0; wait tile0, keep 2 in flight
    STA8(0, 0); STB8(0, 0); STA8(0, 1); STB8(0, 1); STB8(1, 0); STA8(1, 0);
    asm volatile("s_waitcnt vmcnt(4)" ::: "memory");
    __builtin_amdgcn_s_barrier();

#define PHASE8(QM, QN, ...)                                                   \
    {                                                                         \
        const unsigned short* Ap_ = As + buf * 16384 + (QM) * 8192;           \
        const unsigned short* Bp_ = Bs + buf * 16384 + (QN) * 8192;           \
        bf16x8 af[4][2], wf[2][2];                                            \
        _Pragma("unroll") for (int mf = 0; mf < 4; ++mf) {                    \
            int ia = wr * 64 + mf * 16 + fr;                                  \
            af[mf][0] = *(const bf16x8*)&Ap_[ia * 64 + ch0 * 8];              \
            af[mf][1] = *(const bf16x8*)&Ap_[ia * 64 + ch1 * 8];              \
        }                                                                     \
        _Pragma("unroll") for (int nf = 0; nf < 2; ++nf) {                    \
            int ib = wc * 32 + nf * 16 + fr;                                  \
            wf[nf][0] = *(const bf16x8*)&Bp_[ib * 64 + ch0 * 8];              \
            wf[nf][1] = *(const bf16x8*)&Bp_[ib * 64 + ch1 * 8];              \
        }                                                                     \
        __VA_ARGS__                                                           \
        __builtin_amdgcn_s_barrier();                                         \
        asm volatile("s_waitcnt lgkmcnt(0)" ::: "memory");                    \
        __builtin_amdgcn_s_setprio(1);                                        \
        _Pragma("unroll") for (int mf = 0; mf < 4; ++mf)                      \
            _Pragma("unroll") for (int nf = 0; nf < 2; ++nf) {                \
                acc[QM][QN][mf][nf] = __builtin_amdgcn_mfma_f32_16x16x32_bf16(\
                    af[mf][0], wf[nf][0], acc[QM][QN][mf][nf], 0, 0, 0);      \
                acc[QM][QN][mf][nf] = __builtin_amdgcn_mfma_f32_16x16x32_bf16(\
                    af[mf][1], wf[nf][1], acc[QM][QN][mf][nf], 0, 0, 0);      \
            }                                                                 \
        __builtin_amdgcn_s_setprio(0);                                        \
    }

    for (int t = 0; t < NT; ++t) {
        const int buf = t & 1;
        // p0: Q(0,0) reads Ah0,Bh0 ; stage next tile's Ah1,Bh1
        PHASE8(0, 0, { if (t + 1 < NT) { STA8(t + 1, 1); STB8(t + 1, 1); } })
        __builtin_amdgcn_s_barrier();
        // p1: Q(1,0) reads Ah1,Bh0 (Bh0 retires)
        PHASE8(1, 0, {})
        __builtin_amdgcn_s_barrier();
        // p2: Q(0,1) reads Ah0,Bh1 (Ah0 retires); stage tile+2 Bh0
        PHASE8(0, 1, { if (t + 2 < NT) STB8(t + 2, 0); })
        __builtin_amdgcn_s_barrier();
        // p3: Q(1,1) reads Ah1,Bh1 (both retire); stage tile+2 Ah0
        PHASE8(1, 1, { if (t + 2 < NT) STA8(t + 2, 0); })
        // tile boundary: counted wait (2 half-tiles stay in flight)
        if (t < NT - 1) {
            if (t <= NT - 3) asm volatile("s_waitcnt vmcnt(4)" ::: "memory");
            else             asm volatile("s_waitcnt vmcnt(0)" ::: "memory");
        }
        __builtin_amdgcn_s_barrier();
    }
#undef PHASE8
#undef STA8
#undef STB8

    // epilogue: C/D layout col = lane&15, row = (lane>>4)*4 + j
#pragma unroll
    for (int qm = 0; qm < 2; ++qm)
#pragma unroll
        for (int qn = 0; qn < 2; ++qn)
#pragma unroll
            for (int nf = 0; nf < 2; ++nf) {
                const int col = col0 + wc * 64 + qn * 32 + nf * 16 + fr;
                const float bv = bias[col];
#pragma unroll
                for (int mf = 0; mf < 4; ++mf) {
                    const int rowb = row0 + wr * 128 + qm * 64 + mf * 16 + fk * 4;
#pragma unroll
                    for (int j = 0; j < 4; ++j)
                        C[(size_t)(rowb + j) * ldc + col] =
                            acc[qm][qn][mf][nf][j] + bv;
                }
            }
}

// ============================================================================
extern "C" void kernel_launch(void* const* d_in, const int* in_sizes, int n_in,
                              void* d_out, int out_size, void* d_ws, size_t ws_size,
                              hipStream_t stream)
{
    (void)in_sizes; (void)n_in; (void)out_size; (void)ws_size;

    const float* input  = (const float*)d_in[0];
    const float* hidden = (const float*)d_in[1];
    const float* b_ih0  = (const float*)d_in[4];
    const float* b_hh0  = (const float*)d_in[5];
    const float* b_ih1  = (const float*)d_in[8];
    const float* b_hh1  = (const float*)d_in[9];
    const float* b_out  = (const float*)d_in[11];

    float* out = (float*)d_out;                    // [4096,4096]
    float* h0  = out + (size_t)4096 * 4096;
    float* h1  = h0 + (size_t)4096 * 1024;

    unsigned short* xb    = (unsigned short*)d_ws;
    unsigned short* hidb  = xb    + (size_t)4096 * 1024;
    unsigned short* h0b   = hidb  + (size_t)2 * 4096 * 1024;
    unsigned short* Wih0b = h0b   + (size_t)4096 * 1024;
    unsigned short* Whh0b = Wih0b + (size_t)1024 * 1024;
    unsigned short* Wih1b = Whh0b + (size_t)1024 * 1024;
    unsigned short* Whh1b = Wih1b + (size_t)1024 * 1024;
    unsigned short* Woutb = Whh1b + (size_t)1024 * 1024;
    unsigned short* hid0b = hidb;
    unsigned short* hid1b = hidb + (size_t)4096 * 1024;

    CvtArgs ca;
    ca.seg[0] = { input,                 xb,    4096u * 1024 / 8 };
    ca.seg[1] = { hidden,                hidb,  2u * 4096 * 1024 / 8 };
    ca.seg[2] = { (const float*)d_in[2], Wih0b, 1024u * 1024 / 8 };
    ca.seg[3] = { (const float*)d_in[3], Whh0b, 1024u * 1024 / 8 };
    ca.seg[4] = { (const float*)d_in[6], Wih1b, 1024u * 1024 / 8 };
    ca.seg[5] = { (const float*)d_in[7], Whh1b, 1024u * 1024 / 8 };
    ca.seg[6] = { (const float*)d_in[10],Woutb, 4096u * 2048 / 8 };
    hipLaunchKernelGGL(f2b_multi, dim3(12288), dim3(256), 0, stream, ca);

    // GEMM1: h0 = tanh(x@Wih0^T + hid0@Whh0^T + b), 128x64 tiles, 512 blocks
    GemmP p1;
    p1.Aa = xb;    p1.Ab = hid0b; p1.lda = 1024;
    p1.Wa = Wih0b; p1.Wb = Whh0b; p1.ldw = 1024;
    p1.ba = b_ih0; p1.bb = b_hh0;
    p1.C = h0; p1.ldc = 1024; p1.Cb = h0b; p1.ldcb = 1024;
    p1.nx = 16; p1.nb = 512; p1.do_tanh = 1;
    hipLaunchKernelGGL(gemm1_k, dim3(512), dim3(256), 0, stream, p1);

    // GEMM3: logits = x@W_out[:,:1024]^T + h0@W_out[:,1024:]^T + b_out
    hipLaunchKernelGGL(gemm8p, dim3(256), dim3(512), 0, stream,
                       xb, h0b, Woutb, Woutb + 1024, 1024, 2048,
                       b_out, out, 4096, 16);

    // GEMM2 (256 blocks) + log_softmax (4096 rows), one dispatch
    GemmP p2;
    p2.Aa = h0b;   p2.Ab = hid1b; p2.lda = 1024;
    p2.Wa = Wih1b; p2.Wb = Whh1b; p2.ldw = 1024;
    p2.ba = b_ih1; p2.bb = b_hh1;
    p2.C = h1; p2.ldc = 1024; p2.Cb = nullptr; p2.ldcb = 0;
    p2.nx = 8; p2.nb = 256; p2.do_tanh = 1;
    hipLaunchKernelGGL(g2sm_k, dim3(4352), dim3(256), 0, stream, p2, out);
}